// Round 1
// baseline (120.363 us; speedup 1.0000x reference)
//
#include <hip/hip_runtime.h>
#include <math.h>

#define NV 24
#define NB 8
#define NS 512
#define NTOK 4096       // NB*NS
#define H1 128
#define H2 64
#define SH1 256
#define SH2 128
#define IH 32
#define NP 576          // NV*NV

// ---------------- ws layout (floats) ----------------
// [0, 12288)              avg (S*V)
// [12288, 12864)          corr (576)
// [12864, 13416)          pmask (24*23)
// [13416, 13440)          has_parent (24)

// Stage 1a: avg over batch -> (S,V)
__global__ void k_avg(const float* __restrict__ data, float* __restrict__ ws_avg) {
    int idx = blockIdx.x * 256 + threadIdx.x;
    if (idx < NS * NV) {
        float s = 0.f;
#pragma unroll
        for (int b = 0; b < NB; ++b) s += data[b * (NS * NV) + idx];
        ws_avg[idx] = s * (1.f / NB);
    }
}

// Stage 1b: center over S, cov, corr
__global__ void k_corr(const float* __restrict__ ws_avg, float* __restrict__ ws_corr) {
    __shared__ float c[NS * NV];
    __shared__ float colmean[NV];
    __shared__ float cov[NP];
    int tid = threadIdx.x;  // 1024
    for (int i = tid; i < NS * NV; i += 1024) c[i] = ws_avg[i];
    __syncthreads();
    if (tid < NV) {
        float s = 0.f;
        for (int r = 0; r < NS; ++r) s += c[r * NV + tid];
        colmean[tid] = s / NS;
    }
    __syncthreads();
    for (int i = tid; i < NS * NV; i += 1024) c[i] -= colmean[i % NV];
    __syncthreads();
    if (tid < NP) {
        int i = tid / NV, j = tid % NV;
        float s = 0.f;
        for (int r = 0; r < NS; ++r) s += c[r * NV + i] * c[r * NV + j];
        cov[tid] = s;
    }
    __syncthreads();
    if (tid < NP) {
        int i = tid / NV, j = tid % NV;
        float si = sqrtf(cov[i * NV + i]), sj = sqrtf(cov[j * NV + j]);
        float q = fabsf(cov[tid] / (si * sj));
        if (isnan(q)) q = 0.f;
        if (i == j) q = 0.f;
        ws_corr[tid] = q;
    }
}

// Stage 1c: structure MLP 576->256->128->576, sigmoid, triu, masks
__global__ void k_mlp_adj(const float* __restrict__ ws_corr,
                          const float* __restrict__ sW1, const float* __restrict__ sb1,
                          const float* __restrict__ sW2, const float* __restrict__ sb2,
                          const float* __restrict__ sW3, const float* __restrict__ sb3,
                          float* __restrict__ out_adj,
                          float* __restrict__ ws_pmask, float* __restrict__ ws_hasp) {
    __shared__ float corrL[NP];
    __shared__ float h1L[SH1];
    __shared__ float h2L[SH2];
    __shared__ float maskL[NP];
    int t = threadIdx.x;  // 256
    for (int i = t; i < NP; i += 256) corrL[i] = ws_corr[i];
    __syncthreads();
    {
        float a = sb1[t];
        for (int k = 0; k < NP; ++k) a = fmaf(corrL[k], sW1[k * SH1 + t], a);
        h1L[t] = fmaxf(a, 0.f);
    }
    __syncthreads();
    if (t < SH2) {
        float a = sb2[t];
        for (int k = 0; k < SH1; ++k) a = fmaf(h1L[k], sW2[k * SH2 + t], a);
        h2L[t] = fmaxf(a, 0.f);
    }
    __syncthreads();
    for (int o = t; o < NP; o += 256) {
        float a = sb3[o];
        for (int k = 0; k < SH2; ++k) a = fmaf(h2L[k], sW3[k * NP + o], a);
        float sg = 1.f / (1.f + expf(-a));
        int i = o / NV, j = o % NV;
        float adj = (j > i) ? sg : 0.f;
        out_adj[o] = adj;
        maskL[o] = (adj > 0.5f) ? 1.f : 0.f;
    }
    __syncthreads();
    for (int o = t; o < NV * (NV - 1); o += 256) {
        int v = o / (NV - 1), jj = o % (NV - 1);
        int oth = (jj < v) ? jj : jj + 1;
        ws_pmask[o] = maskL[oth * NV + v];
    }
    if (t < NV) {
        float any = 0.f;
        for (int r = 0; r < NV; ++r) any = fmaxf(any, maskL[r * NV + t]);
        ws_hasp[t] = any;
    }
}

// Stage 2: per-variable 23->128->64->1 MLP over all 4096 tokens
__global__ __launch_bounds__(256) void k_pred(
    const float* __restrict__ data,
    const float* __restrict__ mW1, const float* __restrict__ mb1,
    const float* __restrict__ mW2, const float* __restrict__ mb2,
    const float* __restrict__ mW3, const float* __restrict__ mb3,
    const float* __restrict__ ws_pmask, const float* __restrict__ ws_hasp,
    float* __restrict__ out_pred) {
    int v = blockIdx.x;
    int chunk = blockIdx.y;
    __shared__ float W1t[H1][NV];     // [h][j], j<23 used (transposed for contiguous row reads)
    __shared__ float W2s[H1 * H2];
    __shared__ float W3s[H2];
    __shared__ float b1s[H1];
    __shared__ float b2s[H2];
    __shared__ float pms[NV - 1];
    __shared__ float b3s, hps;
    int t = threadIdx.x;
    for (int idx = t; idx < (NV - 1) * H1; idx += 256) {
        int j = idx / H1, h = idx % H1;
        W1t[h][j] = mW1[v * (NV - 1) * H1 + idx];
    }
    for (int idx = t; idx < H1 * H2; idx += 256) W2s[idx] = mW2[v * H1 * H2 + idx];
    if (t < H2) { W3s[t] = mW3[v * H2 + t]; b2s[t] = mb2[v * H2 + t]; }
    if (t < H1) b1s[t] = mb1[v * H1 + t];
    if (t < NV - 1) pms[t] = ws_pmask[v * (NV - 1) + t];
    if (t == 0) { b3s = mb3[v]; hps = ws_hasp[v]; }
    __syncthreads();

    int n = chunk * 256 + t;
    const float* drow = data + n * NV;
    float d[NV];
#pragma unroll
    for (int j = 0; j < NV; ++j) d[j] = drow[j];
    float dv = d[v];
    float res;
    if (hps > 0.5f) {  // uniform branch per block
        float xin[NV - 1];
#pragma unroll
        for (int j = 0; j < NV - 1; ++j) {
            int src = (j < v) ? j : j + 1;
            xin[j] = d[src] * pms[j];
        }
        float acc[H2];
#pragma unroll
        for (int g = 0; g < H2; ++g) acc[g] = 0.f;
        for (int h = 0; h < H1; ++h) {
            float a = b1s[h];
#pragma unroll
            for (int j = 0; j < NV - 1; ++j) a = fmaf(xin[j], W1t[h][j], a);
            a = fmaxf(a, 0.f);
#pragma unroll
            for (int g = 0; g < H2; ++g) acc[g] = fmaf(a, W2s[h * H2 + g], acc[g]);
        }
        float ov = b3s;
#pragma unroll
        for (int g = 0; g < H2; ++g) ov = fmaf(fmaxf(acc[g] + b2s[g], 0.f), W3s[g], ov);
        res = ov;
    } else {
        res = dv;
    }
    out_pred[n * NV + v] = res;
}

// Stage 3: pairwise 2->32->1 MLPs, mean sigmoid over 4096 samples
__global__ __launch_bounds__(256) void k_ind(
    const float* __restrict__ data,
    const float* __restrict__ iW1, const float* __restrict__ ib1,
    const float* __restrict__ iW2, const float* __restrict__ ib2,
    float* __restrict__ out_ind) {
    int p = blockIdx.x;
    int i = p / NV, j = p % NV;
    int t = threadIdx.x;
    float w0[IH], w1[IH], bb[IH], w2[IH];
#pragma unroll
    for (int h = 0; h < IH; ++h) {
        w0[h] = iW1[p * 2 * IH + h];
        w1[h] = iW1[p * 2 * IH + IH + h];
        bb[h] = ib1[p * IH + h];
        w2[h] = iW2[p * IH + h];
    }
    float b2v = ib2[p];
    float acc = 0.f;
    for (int k = 0; k < NTOK / 256; ++k) {
        int n = k * 256 + t;
        float di = data[n * NV + i];
        float dj = data[n * NV + j];
        float s = b2v;
#pragma unroll
        for (int h = 0; h < IH; ++h) {
            float a = fmaf(di, w0[h], fmaf(dj, w1[h], bb[h]));
            a = fmaxf(a, 0.f);
            s = fmaf(a, w2[h], s);
        }
        acc += 1.f / (1.f + expf(-s));
    }
    __shared__ float red[256];
    red[t] = acc;
    __syncthreads();
    for (int st = 128; st > 0; st >>= 1) {
        if (t < st) red[t] += red[t + st];
        __syncthreads();
    }
    if (t == 0) out_ind[p] = red[0] * (1.f / NTOK);
}

extern "C" void kernel_launch(void* const* d_in, const int* in_sizes, int n_in,
                              void* d_out, int out_size, void* d_ws, size_t ws_size,
                              hipStream_t stream) {
    const float* data = (const float*)d_in[0];
    const float* sW1 = (const float*)d_in[1];
    const float* sb1 = (const float*)d_in[2];
    const float* sW2 = (const float*)d_in[3];
    const float* sb2 = (const float*)d_in[4];
    const float* sW3 = (const float*)d_in[5];
    const float* sb3 = (const float*)d_in[6];
    const float* mW1 = (const float*)d_in[7];
    const float* mb1 = (const float*)d_in[8];
    const float* mW2 = (const float*)d_in[9];
    const float* mb2 = (const float*)d_in[10];
    const float* mW3 = (const float*)d_in[11];
    const float* mb3 = (const float*)d_in[12];
    const float* iW1 = (const float*)d_in[13];
    const float* ib1 = (const float*)d_in[14];
    const float* iW2 = (const float*)d_in[15];
    const float* ib2 = (const float*)d_in[16];

    float* out = (float*)d_out;
    float* ws = (float*)d_ws;
    float* ws_avg = ws;
    float* ws_corr = ws + 12288;
    float* ws_pmask = ws + 12288 + 576;
    float* ws_hasp = ws_pmask + NV * (NV - 1);

    k_avg<<<dim3((NS * NV + 255) / 256), dim3(256), 0, stream>>>(data, ws_avg);
    k_corr<<<dim3(1), dim3(1024), 0, stream>>>(ws_avg, ws_corr);
    k_mlp_adj<<<dim3(1), dim3(256), 0, stream>>>(ws_corr, sW1, sb1, sW2, sb2, sW3, sb3,
                                                 out, ws_pmask, ws_hasp);
    dim3 g3(NV, NTOK / 256);
    k_pred<<<g3, dim3(256), 0, stream>>>(data, mW1, mb1, mW2, mb2, mW3, mb3,
                                         ws_pmask, ws_hasp, out + NP);
    k_ind<<<dim3(NP), dim3(256), 0, stream>>>(data, iW1, ib1, iW2, ib2,
                                              out + NP + NTOK * NV);
}

// Round 2
// 102.098 us; speedup vs baseline: 1.1789x; 1.1789x over previous
//
#include <hip/hip_runtime.h>
#include <math.h>

#define NV 24
#define NB 8
#define NS 512
#define NTOK 4096       // NB*NS
#define H1 128
#define H2 64
#define SH1 256
#define SH2 128
#define IH 32
#define NP 576          // NV*NV

// ---------------- ws layout (floats) ----------------
// [0, 12288)          avgT   [NV][NS]   (transposed batch-mean)
// [12288, 12864)      cov    [NP]
// [12864, 13416)      pmask  [NV][NV-1]
// [13416, 13440)      has_parent [NV]
// [13440, 111744)     dataT  [NV][NTOK]

// Transpose data (NTOK x NV) -> dataT (NV x NTOK) for coalesced k_ind reads
__global__ __launch_bounds__(256) void k_transp(const float* __restrict__ data,
                                                float* __restrict__ dataT) {
    int idx = blockIdx.x * 256 + threadIdx.x;
    if (idx < NTOK * NV) {
        int n = idx / NV, v = idx % NV;
        dataT[v * NTOK + n] = data[idx];
    }
}

// Batch-average -> avgT[v][s]
__global__ __launch_bounds__(256) void k_avg(const float* __restrict__ data,
                                             float* __restrict__ avgT) {
    int idx = blockIdx.x * 256 + threadIdx.x;  // idx = v*NS + s
    if (idx < NS * NV) {
        int v = idx / NS, s = idx % NS;
        float acc = 0.f;
#pragma unroll
        for (int b = 0; b < NB; ++b) acc += data[b * (NS * NV) + s * NV + v];
        avgT[idx] = acc * (1.f / NB);
    }
}

// cov[i][j] = sum_s (avg[s,i]-m_i)(avg[s,j]-m_j)   -- one wave per (i,j)
__global__ __launch_bounds__(64) void k_cov(const float* __restrict__ avgT,
                                            float* __restrict__ cov) {
    int p = blockIdx.x;
    int i = p / NV, j = p % NV;
    int l = threadIdx.x;
    const float* ri = avgT + i * NS;
    const float* rj = avgT + j * NS;
    float si = 0.f, sj = 0.f;
#pragma unroll
    for (int k = 0; k < NS / 64; ++k) { si += ri[k * 64 + l]; sj += rj[k * 64 + l]; }
#pragma unroll
    for (int o = 32; o > 0; o >>= 1) { si += __shfl_down(si, o); sj += __shfl_down(sj, o); }
    float mi = __shfl(si, 0) * (1.f / NS);
    float mj = __shfl(sj, 0) * (1.f / NS);
    float sd = 0.f;
#pragma unroll
    for (int k = 0; k < NS / 64; ++k)
        sd = fmaf(ri[k * 64 + l] - mi, rj[k * 64 + l] - mj, sd);
#pragma unroll
    for (int o = 32; o > 0; o >>= 1) sd += __shfl_down(sd, o);
    if (l == 0) cov[p] = sd;
}

// corr from cov + structure MLP 576->256->128->576 + masks
__global__ __launch_bounds__(256) void k_mlp_adj(
    const float* __restrict__ cov,
    const float* __restrict__ sW1, const float* __restrict__ sb1,
    const float* __restrict__ sW2, const float* __restrict__ sb2,
    const float* __restrict__ sW3, const float* __restrict__ sb3,
    float* __restrict__ out_adj,
    float* __restrict__ ws_pmask, float* __restrict__ ws_hasp) {
    __shared__ float covL[NP];
    __shared__ float stdL[NV];
    __shared__ float corrL[NP];
    __shared__ float h1L[SH1];
    __shared__ float h2L[SH2];
    __shared__ float maskL[NP];
    int t = threadIdx.x;  // 256
    for (int o = t; o < NP; o += 256) covL[o] = cov[o];
    __syncthreads();
    if (t < NV) stdL[t] = sqrtf(covL[t * (NV + 1)]);
    __syncthreads();
    for (int o = t; o < NP; o += 256) {
        int i = o / NV, j = o % NV;
        float q = fabsf(covL[o] / (stdL[i] * stdL[j]));
        if (isnan(q)) q = 0.f;
        if (i == j) q = 0.f;
        corrL[o] = q;
    }
    __syncthreads();
    {
        float a = sb1[t];
        for (int k = 0; k < NP; ++k) a = fmaf(corrL[k], sW1[k * SH1 + t], a);
        h1L[t] = fmaxf(a, 0.f);
    }
    __syncthreads();
    if (t < SH2) {
        float a = sb2[t];
        for (int k = 0; k < SH1; ++k) a = fmaf(h1L[k], sW2[k * SH2 + t], a);
        h2L[t] = fmaxf(a, 0.f);
    }
    __syncthreads();
    for (int o = t; o < NP; o += 256) {
        float a = sb3[o];
        for (int k = 0; k < SH2; ++k) a = fmaf(h2L[k], sW3[k * NP + o], a);
        float sg = 1.f / (1.f + expf(-a));
        int i = o / NV, j = o % NV;
        float adj = (j > i) ? sg : 0.f;
        out_adj[o] = adj;
        maskL[o] = (adj > 0.5f) ? 1.f : 0.f;
    }
    __syncthreads();
    for (int o = t; o < NV * (NV - 1); o += 256) {
        int v = o / (NV - 1), jj = o % (NV - 1);
        int oth = (jj < v) ? jj : jj + 1;
        ws_pmask[o] = maskL[oth * NV + v];
    }
    if (t < NV) {
        float any = 0.f;
        for (int r = 0; r < NV; ++r) any = fmaxf(any, maskL[r * NV + t]);
        ws_hasp[t] = any;
    }
}

// Stage 2: per-variable 23->128->64->1 MLP, float4 LDS weight reads
__global__ __launch_bounds__(256) void k_pred(
    const float* __restrict__ data,
    const float* __restrict__ mW1, const float* __restrict__ mb1,
    const float* __restrict__ mW2, const float* __restrict__ mb2,
    const float* __restrict__ mW3, const float* __restrict__ mb3,
    const float* __restrict__ ws_pmask, const float* __restrict__ ws_hasp,
    float* __restrict__ out_pred) {
    int v = blockIdx.x;
    int chunk = blockIdx.y;
    __shared__ float4 W1s4[H1 * 6];    // row h: 23 weights + bias in slot 23
    __shared__ float4 W2s4[H1 * 16];   // row h: 64 weights
    __shared__ float b2s[H2];
    __shared__ float W3s[H2];
    __shared__ float pms[NV - 1];
    __shared__ float b3s, hps;
    float* W1f = (float*)W1s4;
    float* W2f = (float*)W2s4;
    int t = threadIdx.x;
    // stage W1 transposed: W1f[h*24 + j] = mW1[v][j][h]
    for (int idx = t; idx < (NV - 1) * H1; idx += 256) {
        int j = idx / H1, h = idx % H1;
        W1f[h * 24 + j] = mW1[v * (NV - 1) * H1 + idx];
    }
    if (t < H1) W1f[t * 24 + 23] = mb1[v * H1 + t];   // bias in pad slot
    for (int idx = t; idx < H1 * H2; idx += 256) W2f[idx] = mW2[v * H1 * H2 + idx];
    if (t < H2) { W3s[t] = mW3[v * H2 + t]; b2s[t] = mb2[v * H2 + t]; }
    if (t < NV - 1) pms[t] = ws_pmask[v * (NV - 1) + t];
    if (t == 0) { b3s = mb3[v]; hps = ws_hasp[v]; }
    __syncthreads();

    int n = chunk * 256 + t;
    const float4* drow4 = (const float4*)(data + n * NV);
    float d[NV];
#pragma unroll
    for (int q = 0; q < 6; ++q) {
        float4 u = drow4[q];
        d[q * 4 + 0] = u.x; d[q * 4 + 1] = u.y; d[q * 4 + 2] = u.z; d[q * 4 + 3] = u.w;
    }
    float dv = d[v];
    float res;
    if (hps > 0.5f) {  // uniform per block
        float xin[24];
#pragma unroll
        for (int j = 0; j < NV - 1; ++j) {
            int src = (j < v) ? j : j + 1;
            xin[j] = d[src] * pms[j];
        }
        xin[23] = 1.0f;  // multiplies the bias slot
        float acc[H2];
#pragma unroll
        for (int g = 0; g < H2; ++g) acc[g] = 0.f;
        for (int h = 0; h < H1; ++h) {
            float a = 0.f;
#pragma unroll
            for (int q = 0; q < 6; ++q) {
                float4 w = W1s4[h * 6 + q];
                a = fmaf(xin[q * 4 + 0], w.x, a);
                a = fmaf(xin[q * 4 + 1], w.y, a);
                a = fmaf(xin[q * 4 + 2], w.z, a);
                a = fmaf(xin[q * 4 + 3], w.w, a);
            }
            a = fmaxf(a, 0.f);
#pragma unroll
            for (int q = 0; q < 16; ++q) {
                float4 w = W2s4[h * 16 + q];
                acc[q * 4 + 0] = fmaf(a, w.x, acc[q * 4 + 0]);
                acc[q * 4 + 1] = fmaf(a, w.y, acc[q * 4 + 1]);
                acc[q * 4 + 2] = fmaf(a, w.z, acc[q * 4 + 2]);
                acc[q * 4 + 3] = fmaf(a, w.w, acc[q * 4 + 3]);
            }
        }
        float ov = b3s;
#pragma unroll
        for (int g = 0; g < H2; ++g)
            ov = fmaf(fmaxf(acc[g] + b2s[g], 0.f), W3s[g], ov);
        res = ov;
    } else {
        res = dv;
    }
    out_pred[n * NV + v] = res;
}

// Stage 3: pairwise 2->32->1 MLPs over 4096 samples, coalesced via dataT
__global__ __launch_bounds__(256) void k_ind(
    const float* __restrict__ dataT,
    const float* __restrict__ iW1, const float* __restrict__ ib1,
    const float* __restrict__ iW2, const float* __restrict__ ib2,
    float* __restrict__ out_ind) {
    int p = blockIdx.x;
    int i = p / NV, j = p % NV;
    int t = threadIdx.x;
    float w0[IH], w1[IH], bb[IH], w2[IH];
    const float4* A4 = (const float4*)(iW1 + p * 2 * IH);
    const float4* B4 = (const float4*)(ib1 + p * IH);
    const float4* C4 = (const float4*)(iW2 + p * IH);
#pragma unroll
    for (int q = 0; q < 8; ++q) {
        float4 u = A4[q];
        w0[q * 4 + 0] = u.x; w0[q * 4 + 1] = u.y; w0[q * 4 + 2] = u.z; w0[q * 4 + 3] = u.w;
        float4 v4 = A4[8 + q];
        w1[q * 4 + 0] = v4.x; w1[q * 4 + 1] = v4.y; w1[q * 4 + 2] = v4.z; w1[q * 4 + 3] = v4.w;
        float4 b4 = B4[q];
        bb[q * 4 + 0] = b4.x; bb[q * 4 + 1] = b4.y; bb[q * 4 + 2] = b4.z; bb[q * 4 + 3] = b4.w;
        float4 c4 = C4[q];
        w2[q * 4 + 0] = c4.x; w2[q * 4 + 1] = c4.y; w2[q * 4 + 2] = c4.z; w2[q * 4 + 3] = c4.w;
    }
    float b2v = ib2[p];
    const float* di_p = dataT + i * NTOK;
    const float* dj_p = dataT + j * NTOK;
    float acc = 0.f;
#pragma unroll 2
    for (int k = 0; k < NTOK / 256; ++k) {
        int n = k * 256 + t;
        float di = di_p[n];
        float dj = dj_p[n];
        float s = b2v;
#pragma unroll
        for (int h = 0; h < IH; ++h) {
            float a = fmaf(di, w0[h], fmaf(dj, w1[h], bb[h]));
            a = fmaxf(a, 0.f);
            s = fmaf(a, w2[h], s);
        }
        acc += 1.f / (1.f + expf(-s));
    }
    __shared__ float red[256];
    red[t] = acc;
    __syncthreads();
    for (int st = 128; st > 0; st >>= 1) {
        if (t < st) red[t] += red[t + st];
        __syncthreads();
    }
    if (t == 0) out_ind[p] = red[0] * (1.f / NTOK);
}

extern "C" void kernel_launch(void* const* d_in, const int* in_sizes, int n_in,
                              void* d_out, int out_size, void* d_ws, size_t ws_size,
                              hipStream_t stream) {
    const float* data = (const float*)d_in[0];
    const float* sW1 = (const float*)d_in[1];
    const float* sb1 = (const float*)d_in[2];
    const float* sW2 = (const float*)d_in[3];
    const float* sb2 = (const float*)d_in[4];
    const float* sW3 = (const float*)d_in[5];
    const float* sb3 = (const float*)d_in[6];
    const float* mW1 = (const float*)d_in[7];
    const float* mb1 = (const float*)d_in[8];
    const float* mW2 = (const float*)d_in[9];
    const float* mb2 = (const float*)d_in[10];
    const float* mW3 = (const float*)d_in[11];
    const float* mb3 = (const float*)d_in[12];
    const float* iW1 = (const float*)d_in[13];
    const float* ib1 = (const float*)d_in[14];
    const float* iW2 = (const float*)d_in[15];
    const float* ib2 = (const float*)d_in[16];

    float* out = (float*)d_out;
    float* ws = (float*)d_ws;
    float* ws_avgT = ws;
    float* ws_cov = ws + 12288;
    float* ws_pmask = ws + 12288 + 576;
    float* ws_hasp = ws_pmask + NV * (NV - 1);
    float* ws_dataT = ws + 13440;

    k_transp<<<dim3((NTOK * NV + 255) / 256), dim3(256), 0, stream>>>(data, ws_dataT);
    k_avg<<<dim3((NS * NV + 255) / 256), dim3(256), 0, stream>>>(data, ws_avgT);
    k_cov<<<dim3(NP), dim3(64), 0, stream>>>(ws_avgT, ws_cov);
    k_mlp_adj<<<dim3(1), dim3(256), 0, stream>>>(ws_cov, sW1, sb1, sW2, sb2, sW3, sb3,
                                                 out, ws_pmask, ws_hasp);
    dim3 g3(NV, NTOK / 256);
    k_pred<<<g3, dim3(256), 0, stream>>>(data, mW1, mb1, mW2, mb2, mW3, mb3,
                                         ws_pmask, ws_hasp, out + NP);
    k_ind<<<dim3(NP), dim3(256), 0, stream>>>(ws_dataT, iW1, ib1, iW2, ib2,
                                              out + NP + NTOK * NV);
}

// Round 3
// 56.994 us; speedup vs baseline: 2.1118x; 1.7914x over previous
//
#include <hip/hip_runtime.h>
#include <math.h>

#define NV 24
#define NB 8
#define NS 512
#define NTOK 4096       // NB*NS
#define H1 128
#define H2 64
#define SH1 256
#define SH2 128
#define IH 32
#define NP 576          // NV*NV

typedef short bf16x8 __attribute__((ext_vector_type(8)));
typedef float f32x4 __attribute__((ext_vector_type(4)));

__device__ __forceinline__ short f2bf(float f) {
    union { float f; unsigned u; } x; x.f = f;
    unsigned r = x.u + 0x7fffu + ((x.u >> 16) & 1u);   // RNE
    return (short)(r >> 16);
}

// ---------------- ws layout (floats) ----------------
// [0, 12288)          avgT   [NV][NS]
// [12288, 12864)      cov    [NP]
// [12864, 13120)      h1     [SH1]
// [13120, 13248)      h2     [SH2]
// [13440, 111744)     dataT  [NV][NTOK]

__global__ __launch_bounds__(256) void k_transp(const float* __restrict__ data,
                                                float* __restrict__ dataT) {
    int idx = blockIdx.x * 256 + threadIdx.x;
    if (idx < NTOK * NV) {
        int n = idx / NV, v = idx % NV;
        dataT[v * NTOK + n] = data[idx];
    }
}

__global__ __launch_bounds__(256) void k_avg(const float* __restrict__ data,
                                             float* __restrict__ avgT) {
    int idx = blockIdx.x * 256 + threadIdx.x;  // idx = v*NS + s
    if (idx < NS * NV) {
        int v = idx / NS, s = idx % NS;
        float acc = 0.f;
#pragma unroll
        for (int b = 0; b < NB; ++b) acc += data[b * (NS * NV) + s * NV + v];
        avgT[idx] = acc * (1.f / NB);
    }
}

__global__ __launch_bounds__(64) void k_cov(const float* __restrict__ avgT,
                                            float* __restrict__ cov) {
    int p = blockIdx.x;
    int i = p / NV, j = p % NV;
    int l = threadIdx.x;
    const float* ri = avgT + i * NS;
    const float* rj = avgT + j * NS;
    float si = 0.f, sj = 0.f;
#pragma unroll
    for (int k = 0; k < NS / 64; ++k) { si += ri[k * 64 + l]; sj += rj[k * 64 + l]; }
#pragma unroll
    for (int o = 32; o > 0; o >>= 1) { si += __shfl_down(si, o); sj += __shfl_down(sj, o); }
    float mi = __shfl(si, 0) * (1.f / NS);
    float mj = __shfl(sj, 0) * (1.f / NS);
    float sd = 0.f;
#pragma unroll
    for (int k = 0; k < NS / 64; ++k)
        sd = fmaf(ri[k * 64 + l] - mi, rj[k * 64 + l] - mj, sd);
#pragma unroll
    for (int o = 32; o > 0; o >>= 1) sd += __shfl_down(sd, o);
    if (l == 0) cov[p] = sd;
}

// layer1 of structure MLP: 576 -> 256, 8 blocks x 32 outputs
__global__ __launch_bounds__(256) void k_mlp1(const float* __restrict__ cov,
                                              const float* __restrict__ sW1,
                                              const float* __restrict__ sb1,
                                              float* __restrict__ h1out) {
    __shared__ float corrL[NP];
    __shared__ float stdL[NV];
    __shared__ float P[256];
    int t = threadIdx.x, b = blockIdx.x;
    if (t < NV) stdL[t] = sqrtf(cov[t * (NV + 1)]);
    __syncthreads();
    for (int o = t; o < NP; o += 256) {
        int i = o / NV, j = o % NV;
        float q = fabsf(cov[o] / (stdL[i] * stdL[j]));
        if (isnan(q)) q = 0.f;
        if (i == j) q = 0.f;
        corrL[o] = q;
    }
    __syncthreads();
    int o = b * 32 + (t & 31);
    int c = t >> 5;
    float p = 0.f;
    for (int k = c * 72; k < c * 72 + 72; ++k)
        p = fmaf(corrL[k], sW1[k * SH1 + o], p);
    P[t] = p;
    __syncthreads();
    if (t < 32) {
        float s = 0.f;
#pragma unroll
        for (int c2 = 0; c2 < 8; ++c2) s += P[c2 * 32 + t];
        h1out[b * 32 + t] = fmaxf(s + sb1[b * 32 + t], 0.f);
    }
}

// layer2: 256 -> 128, 1 block of 128
__global__ __launch_bounds__(128) void k_mlp2(const float* __restrict__ h1,
                                              const float* __restrict__ sW2,
                                              const float* __restrict__ sb2,
                                              float* __restrict__ h2out) {
    __shared__ float h1L[SH1];
    int t = threadIdx.x;
    for (int k = t; k < SH1; k += 128) h1L[k] = h1[k];
    __syncthreads();
    float a = sb2[t];
    for (int k = 0; k < SH1; ++k) a = fmaf(h1L[k], sW2[k * SH2 + t], a);
    h2out[t] = fmaxf(a, 0.f);
}

// layer3: 128 -> 576, sigmoid + triu -> adj. 9 blocks x 64 outputs.
__global__ __launch_bounds__(256) void k_mlp3(const float* __restrict__ h2,
                                              const float* __restrict__ sW3,
                                              const float* __restrict__ sb3,
                                              float* __restrict__ out_adj) {
    __shared__ float h2L[SH2];
    __shared__ float P[256];
    int t = threadIdx.x, b = blockIdx.x;
    if (t < SH2) h2L[t] = h2[t];
    __syncthreads();
    int o = b * 64 + (t & 63);
    int c = t >> 6;
    float p = 0.f;
    for (int k = c * 32; k < c * 32 + 32; ++k)
        p = fmaf(h2L[k], sW3[k * NP + o], p);
    P[t] = p;
    __syncthreads();
    if (t < 64) {
        int oo = b * 64 + t;
        float s = P[t] + P[64 + t] + P[128 + t] + P[192 + t] + sb3[oo];
        float sg = 1.f / (1.f + expf(-s));
        int i = oo / NV, j = oo % NV;
        out_adj[oo] = (j > i) ? sg : 0.f;
    }
}

// Stage 2: per-variable 23->128->64->1 MLP via bf16 MFMA 16x16x32.
// A layout: lane l holds A[l&15][(l>>4)*8 + e]; B: lane l holds B[(l>>4)*8+e][l&15]
// C/D: col = lane&15, row = (lane>>4)*4 + reg   (m89-verified)
__global__ __launch_bounds__(256) void k_pred(
    const float* __restrict__ data,
    const float* __restrict__ mW1, const float* __restrict__ mb1,
    const float* __restrict__ mW2, const float* __restrict__ mb2,
    const float* __restrict__ mW3, const float* __restrict__ mb3,
    const float* __restrict__ adj,
    float* __restrict__ out_pred) {
    const int v = blockIdx.x;
    const int chunk = blockIdx.y;
    const int t = threadIdx.x;

    // has_parent = any(adj[:, v] > 0.5)
    bool hp = false;
#pragma unroll
    for (int r = 0; r < NV; ++r) hp = hp || (adj[r * NV + v] > 0.5f);
    if (!hp) {
        int tok = chunk * 256 + t;
        out_pred[tok * NV + v] = data[tok * NV + v];
        return;
    }

    __shared__ short Xl[256 * 40];      // [tok][40] bf16 rows (32 used), stride 80B
    __shared__ short W1B[32 * 128];     // B-frag layout [nt8][kb4][nn16][e8]
    __shared__ short W2B[128 * 64];     // B-frag layout [s4][nt4][kb4][nn16][e8]
    __shared__ short Hl[4][16 * 128];   // per-wave H tile, XOR-swizzled rows

    // ---- stage X: other-shifted data, bias slot 23 = 1.0, pad 24..31 = 0 ----
    {
        int tok = chunk * 256 + t;
        const float4* dr4 = (const float4*)(data + tok * NV);
        float d[24];
#pragma unroll
        for (int q = 0; q < 6; ++q) {
            float4 u = dr4[q];
            d[q * 4 + 0] = u.x; d[q * 4 + 1] = u.y; d[q * 4 + 2] = u.z; d[q * 4 + 3] = u.w;
        }
        short xr[32];
#pragma unroll
        for (int j = 0; j < 23; ++j) {
            int src = j + (j >= v ? 1 : 0);
            xr[j] = f2bf(d[src]);
        }
        xr[23] = f2bf(1.0f);
#pragma unroll
        for (int j = 24; j < 32; ++j) xr[j] = 0;
        short* xp = Xl + t * 40;
#pragma unroll
        for (int q = 0; q < 4; ++q)
            *(bf16x8*)(xp + q * 8) = *(bf16x8*)(xr + q * 8);
    }
    // ---- stage W1 (parent-mask + bias folded), B-frag layout ----
    for (int idx = t; idx < 32 * 128; idx += 256) {
        int k = idx >> 7, h = idx & 127;
        float val = 0.f;
        if (k < 23) {
            int src = k + (k >= v ? 1 : 0);
            float pm = (adj[src * NV + v] > 0.5f) ? 1.f : 0.f;
            val = mW1[(v * 23 + k) * 128 + h] * pm;
        } else if (k == 23) {
            val = mb1[v * 128 + h];
        }
        int nt = h >> 4, nn = h & 15, kb = (k >> 3) & 3, e = k & 7;
        W1B[((nt * 4 + kb) * 16 + nn) * 8 + e] = f2bf(val);
    }
    // ---- stage W2, B-frag layout ----
    for (int idx = t; idx < 128 * 64; idx += 256) {
        int k = idx >> 6, n = idx & 63;
        float val = mW2[(v * 128 + k) * 64 + n];
        int s = k >> 5, kb = (k >> 3) & 3, e = k & 7, nt = n >> 4, nn = n & 15;
        W2B[(((s * 4 + nt) * 4 + kb) * 16 + nn) * 8 + e] = f2bf(val);
    }
    __syncthreads();

    const int lane = t & 63;
    const int wid = t >> 6;
    const int ml = lane & 15;
    const int kb = lane >> 4;
    short* Hw = &Hl[wid][0];

    // hoist B-fragments into registers (per-lane contiguous 16B reads, conflict-free)
    bf16x8 w1f[8], w2f[16];
#pragma unroll
    for (int nt = 0; nt < 8; ++nt)
        w1f[nt] = *(bf16x8*)(W1B + (nt * 64 + lane) * 8);
#pragma unroll
    for (int q = 0; q < 16; ++q)
        w2f[q] = *(bf16x8*)(W2B + (q * 64 + lane) * 8);

    float b2r[4], w3r[4];
#pragma unroll
    for (int nt = 0; nt < 4; ++nt) {
        b2r[nt] = mb2[v * 64 + nt * 16 + ml];
        w3r[nt] = mW3[v * 64 + nt * 16 + ml];
    }
    float b3v = mb3[v];

#pragma unroll
    for (int mt = 0; mt < 4; ++mt) {
        int lt = wid * 64 + mt * 16 + ml;   // local token index for A-frag row
        bf16x8 a1 = *(bf16x8*)(Xl + lt * 40 + kb * 8);
        f32x4 c1[8] = {};
#pragma unroll
        for (int nt = 0; nt < 8; ++nt)
            c1[nt] = __builtin_amdgcn_mfma_f32_16x16x32_bf16(a1, w1f[nt], c1[nt], 0, 0, 0);
        // relu -> bf16 -> H tile (XOR-swizzled to avoid 32-way bank conflicts)
#pragma unroll
        for (int nt = 0; nt < 8; ++nt) {
#pragma unroll
            for (int r = 0; r < 4; ++r) {
                int m = kb * 4 + r;
                int h = nt * 16 + ml;
                int bo = (m * 256 + h * 2) ^ ((m & 7) << 4);
                *(short*)((char*)Hw + bo) = f2bf(fmaxf(c1[nt][r], 0.f));
            }
        }
        f32x4 c2[4] = {};
#pragma unroll
        for (int s = 0; s < 4; ++s) {
            int c0 = s * 32 + kb * 8;
            int bo = (ml * 256 + c0 * 2) ^ ((ml & 7) << 4);
            bf16x8 a2 = *(bf16x8*)((char*)Hw + bo);
#pragma unroll
            for (int nt = 0; nt < 4; ++nt)
                c2[nt] = __builtin_amdgcn_mfma_f32_16x16x32_bf16(a2, w2f[s * 4 + nt], c2[nt], 0, 0, 0);
        }
        // layer 3: relu(c2 + b2) . W3, reduce across the 16 lanes holding one token
        float sacc[4] = {0.f, 0.f, 0.f, 0.f};
#pragma unroll
        for (int nt = 0; nt < 4; ++nt) {
#pragma unroll
            for (int r = 0; r < 4; ++r)
                sacc[r] += fmaxf(c2[nt][r] + b2r[nt], 0.f) * w3r[nt];
        }
#pragma unroll
        for (int o = 1; o < 16; o <<= 1) {
#pragma unroll
            for (int r = 0; r < 4; ++r)
                sacc[r] += __shfl_xor(sacc[r], o);
        }
        if (ml == 0) {
            int tokb = chunk * 256 + wid * 64 + mt * 16 + kb * 4;
#pragma unroll
            for (int r = 0; r < 4; ++r)
                out_pred[(tokb + r) * NV + v] = sacc[r] + b3v;
        }
    }
}

__global__ __launch_bounds__(256) void k_ind(
    const float* __restrict__ dataT,
    const float* __restrict__ iW1, const float* __restrict__ ib1,
    const float* __restrict__ iW2, const float* __restrict__ ib2,
    float* __restrict__ out_ind) {
    int p = blockIdx.x;
    int i = p / NV, j = p % NV;
    int t = threadIdx.x;
    float w0[IH], w1[IH], bb[IH], w2[IH];
    const float4* A4 = (const float4*)(iW1 + p * 2 * IH);
    const float4* B4 = (const float4*)(ib1 + p * IH);
    const float4* C4 = (const float4*)(iW2 + p * IH);
#pragma unroll
    for (int q = 0; q < 8; ++q) {
        float4 u = A4[q];
        w0[q * 4 + 0] = u.x; w0[q * 4 + 1] = u.y; w0[q * 4 + 2] = u.z; w0[q * 4 + 3] = u.w;
        float4 v4 = A4[8 + q];
        w1[q * 4 + 0] = v4.x; w1[q * 4 + 1] = v4.y; w1[q * 4 + 2] = v4.z; w1[q * 4 + 3] = v4.w;
        float4 b4 = B4[q];
        bb[q * 4 + 0] = b4.x; bb[q * 4 + 1] = b4.y; bb[q * 4 + 2] = b4.z; bb[q * 4 + 3] = b4.w;
        float4 c4 = C4[q];
        w2[q * 4 + 0] = c4.x; w2[q * 4 + 1] = c4.y; w2[q * 4 + 2] = c4.z; w2[q * 4 + 3] = c4.w;
    }
    float b2v = ib2[p];
    const float* di_p = dataT + i * NTOK;
    const float* dj_p = dataT + j * NTOK;
    float acc = 0.f;
#pragma unroll 2
    for (int k = 0; k < NTOK / 256; ++k) {
        int n = k * 256 + t;
        float di = di_p[n];
        float dj = dj_p[n];
        float s = b2v;
#pragma unroll
        for (int h = 0; h < IH; ++h) {
            float a = fmaf(di, w0[h], fmaf(dj, w1[h], bb[h]));
            a = fmaxf(a, 0.f);
            s = fmaf(a, w2[h], s);
        }
        acc += 1.f / (1.f + expf(-s));
    }
    __shared__ float red[256];
    red[t] = acc;
    __syncthreads();
    for (int st = 128; st > 0; st >>= 1) {
        if (t < st) red[t] += red[t + st];
        __syncthreads();
    }
    if (t == 0) out_ind[p] = red[0] * (1.f / NTOK);
}

extern "C" void kernel_launch(void* const* d_in, const int* in_sizes, int n_in,
                              void* d_out, int out_size, void* d_ws, size_t ws_size,
                              hipStream_t stream) {
    const float* data = (const float*)d_in[0];
    const float* sW1 = (const float*)d_in[1];
    const float* sb1 = (const float*)d_in[2];
    const float* sW2 = (const float*)d_in[3];
    const float* sb2 = (const float*)d_in[4];
    const float* sW3 = (const float*)d_in[5];
    const float* sb3 = (const float*)d_in[6];
    const float* mW1 = (const float*)d_in[7];
    const float* mb1 = (const float*)d_in[8];
    const float* mW2 = (const float*)d_in[9];
    const float* mb2 = (const float*)d_in[10];
    const float* mW3 = (const float*)d_in[11];
    const float* mb3 = (const float*)d_in[12];
    const float* iW1 = (const float*)d_in[13];
    const float* ib1 = (const float*)d_in[14];
    const float* iW2 = (const float*)d_in[15];
    const float* ib2 = (const float*)d_in[16];

    float* out = (float*)d_out;
    float* ws = (float*)d_ws;
    float* ws_avgT = ws;
    float* ws_cov = ws + 12288;
    float* ws_h1 = ws + 12864;
    float* ws_h2 = ws + 13120;
    float* ws_dataT = ws + 13440;

    k_transp<<<dim3((NTOK * NV + 255) / 256), dim3(256), 0, stream>>>(data, ws_dataT);
    k_avg<<<dim3((NS * NV + 255) / 256), dim3(256), 0, stream>>>(data, ws_avgT);
    k_cov<<<dim3(NP), dim3(64), 0, stream>>>(ws_avgT, ws_cov);
    k_mlp1<<<dim3(8), dim3(256), 0, stream>>>(ws_cov, sW1, sb1, ws_h1);
    k_mlp2<<<dim3(1), dim3(128), 0, stream>>>(ws_h1, sW2, sb2, ws_h2);
    k_mlp3<<<dim3(9), dim3(256), 0, stream>>>(ws_h2, sW3, sb3, out);
    dim3 g3(NV, NTOK / 256);
    k_pred<<<g3, dim3(256), 0, stream>>>(data, mW1, mb1, mW2, mb2, mW3, mb3,
                                         out, out + NP);
    k_ind<<<dim3(NP), dim3(256), 0, stream>>>(ws_dataT, iW1, ib1, iW2, ib2,
                                              out + NP + NTOK * NV);
}